// Round 1
// baseline (693.103 us; speedup 1.0000x reference)
//
#include <hip/hip_runtime.h>
#include <hip/hip_bf16.h>
#include <stdint.h>

#define E_ 8
#define B_ 16384
#define N_ 64
#define H_ 512
#define A_ 8
#define D_ 64

typedef __hip_bfloat16 bf16;
typedef __attribute__((ext_vector_type(8))) short s8v;     // 8 x bf16 (4 VGPRs)
typedef __attribute__((ext_vector_type(4))) float f4v;     // MFMA accum

__device__ __forceinline__ float bf2f(bf16 v) { return __bfloat162float(v); }
__device__ __forceinline__ bf16 f2bf(float v) { return __float2bfloat16(v); }

__device__ __forceinline__ void async_load16(const void* g, void* l) {
    __builtin_amdgcn_global_load_lds(
        (const __attribute__((address_space(1))) void*)g,
        (__attribute__((address_space(3))) void*)l, 16, 0, 0);
}

// ---------------------------------------------------------------------------
// BatchNorm statistics: partial sums per (e, slice, n)
// grid 512 = E*64 slices, 256 threads. Each slice covers 256 rows of B.
// ---------------------------------------------------------------------------
__global__ __launch_bounds__(256) void bnPart(const float* __restrict__ states,
                                              float* __restrict__ part) {
    int blk = blockIdx.x;
    int e = blk >> 6, sl = blk & 63;
    int tid = threadIdx.x, n = tid & 63, rg = tid >> 6;
    const float* base = states + ((long)e * B_ + (long)sl * 256) * 64;
    float s1 = 0.f, s2 = 0.f;
    for (int i = 0; i < 64; ++i) {
        float v = base[(rg + i * 4) * 64 + n];
        s1 += v; s2 += v * v;
    }
    __shared__ float sh[2][4][64];
    sh[0][rg][n] = s1; sh[1][rg][n] = s2;
    __syncthreads();
    if (tid < 64) {
        float t1 = sh[0][0][n] + sh[0][1][n] + sh[0][2][n] + sh[0][3][n];
        float t2 = sh[1][0][n] + sh[1][1][n] + sh[1][2][n] + sh[1][3][n];
        part[((long)blk * 64 + n) * 2 + 0] = t1;
        part[((long)blk * 64 + n) * 2 + 1] = t2;
    }
}

__global__ void bnFin(const float* __restrict__ part, float* __restrict__ mu_rstd) {
    int idx = blockIdx.x * blockDim.x + threadIdx.x;  // e*64+n
    if (idx >= E_ * 64) return;
    int e = idx >> 6, n = idx & 63;
    float s1 = 0.f, s2 = 0.f;
    for (int sl = 0; sl < 64; ++sl) {
        s1 += part[(((long)e * 64 + sl) * 64 + n) * 2 + 0];
        s2 += part[(((long)e * 64 + sl) * 64 + n) * 2 + 1];
    }
    float mu = s1 / (float)B_;
    float var = s2 / (float)B_ - mu * mu;
    mu_rstd[idx * 2 + 0] = mu;
    mu_rstd[idx * 2 + 1] = rsqrtf(var + 1e-5f);
}

// ---------------------------------------------------------------------------
// Weight prep kernels (f32 -> bf16, transposed [N][K] layouts for the GEMM)
// ---------------------------------------------------------------------------
// WT[n*512+k] = W[k*512+n]   (for W_pre, W_actor; 512x512)
__global__ void packT512(const float* __restrict__ in, bf16* __restrict__ out) {
    int idx = blockIdx.x * 256 + threadIdx.x;  // 512*512
    int n = idx >> 9, k = idx & 511;
    out[idx] = f2bf(in[k * 512 + n]);
}

// Head mats [A,H,d] -> WT[(a*64+dd)*512 + h] = W[a][h][dd]
__global__ void packHead(const float* __restrict__ in, bf16* __restrict__ out) {
    int idx = blockIdx.x * 256 + threadIdx.x;  // 512*512
    int n = idx >> 9, h = idx & 511;
    int a = n >> 6, dd = n & 63;
    out[idx] = f2bf(in[((long)a * 512 + h) * 64 + dd]);
}

// WmlT [128][512]: rows 0..63 = W_mean^T, rows 64..127 = W_logstd^T
__global__ void packML(const float* __restrict__ wm, const float* __restrict__ wl,
                       bf16* __restrict__ out) {
    int idx = blockIdx.x * 256 + threadIdx.x;  // 128*512
    int n = idx >> 9, k = idx & 511;
    float v = (n < 64) ? wm[k * 64 + n] : wl[k * 64 + (n - 64)];
    out[idx] = f2bf(v);
}

// Fold BN into encoder weight: WencfT[e][h][n] = W_enc[e][n][h]*rstd[e][n]
// bencf[e][h] = b_enc[e][h] - sum_n mu*rstd*W_enc[e][n][h]
__global__ void foldEnc(const float* __restrict__ W_enc, const float* __restrict__ b_enc,
                        const float* __restrict__ mu_rstd,
                        bf16* __restrict__ WencfT, float* __restrict__ bencf) {
    int idx = blockIdx.x * 256 + threadIdx.x;  // E*H = 4096
    int e = idx >> 9, h = idx & 511;
    float acc = b_enc[e * 512 + h];
    for (int n = 0; n < 64; ++n) {
        float mu = mu_rstd[(e * 64 + n) * 2 + 0];
        float rs = mu_rstd[(e * 64 + n) * 2 + 1];
        float w = W_enc[((long)e * 64 + n) * 512 + h];
        WencfT[((long)e * 512 + h) * 64 + n] = f2bf(w * rs);
        acc -= mu * rs * w;
    }
    bencf[e * 512 + h] = acc;
}

// f32 -> bf16 conversion, float4-vectorized, optional batch (grid.z) strides
__global__ void cvt4_batched(const float* __restrict__ in, bf16* __restrict__ out,
                             long inStrideZ, long outStrideZ, int n4) {
    int i = blockIdx.x * blockDim.x + threadIdx.x;
    if (i >= n4) return;
    const float4* ip = (const float4*)(in + (long)blockIdx.z * inStrideZ);
    float4 v = ip[i];
    bf16 o[4] = {f2bf(v.x), f2bf(v.y), f2bf(v.z), f2bf(v.w)};
    __builtin_memcpy(out + (long)blockIdx.z * outStrideZ + (long)i * 4, o, 8);
}

// ---------------------------------------------------------------------------
// Generic MFMA GEMM:  C[M][Nn] = act(A[M][K] * BT[Nn][K]^T + bias)
// 128x128 tile, BK=64, 256 threads (4 waves in 2x2), 16x16x32 bf16 MFMA,
// global_load_lds width-16 staging (m97 structure).
// ACT: 0 none, 1 leaky, 2 relu (ignored by OUTF 2/3 custom epilogues)
// OUTF: 0 bf16 out; 1 f32 out; 2 final mean/logstd split; 3 keys/vals split
// ---------------------------------------------------------------------------
template <int ACT, int OUTF, bool HAS_BIAS>
__global__ __launch_bounds__(256) void gemm_bt(
    const bf16* __restrict__ Ag, const bf16* __restrict__ Bg,
    const float* __restrict__ bias, const float* __restrict__ bias2,
    void* __restrict__ out, void* __restrict__ out2,
    int M, int Nn, int K, long sA, long sB, long sBias, long sO) {
    const int tid = threadIdx.x, lane = tid & 63, wid = tid >> 6;
    const int wm = wid >> 1, wn = wid & 1;
    const int bm = blockIdx.x, bn = blockIdx.y, bz = blockIdx.z;
    const bf16* Aptr = Ag + (long)bz * sA + (long)bm * 128 * K;
    const bf16* Bptr = Bg + (long)bz * sB + (long)bn * 128 * K;

    __shared__ __align__(16) short sAl[128 * 64];
    __shared__ __align__(16) short sBl[128 * 64];

    f4v acc[4][4];
#pragma unroll
    for (int i = 0; i < 4; ++i)
#pragma unroll
        for (int j = 0; j < 4; ++j) acc[i][j] = f4v{0.f, 0.f, 0.f, 0.f};

    for (int k0 = 0; k0 < K; k0 += 64) {
#pragma unroll
        for (int i = 0; i < 4; ++i) {
            int elem = ((wid * 4 + i) * 64 + lane) * 8;  // 8 bf16 per lane
            int r = elem >> 6, c = elem & 63;
            async_load16(Aptr + (long)r * K + k0 + c, (char*)sAl + (wid * 4 + i) * 1024);
            async_load16(Bptr + (long)r * K + k0 + c, (char*)sBl + (wid * 4 + i) * 1024);
        }
        __syncthreads();
#pragma unroll
        for (int kk = 0; kk < 64; kk += 32) {
            int krow = kk + (lane >> 4) * 8;
            s8v af[4], bfr[4];
#pragma unroll
            for (int mi = 0; mi < 4; ++mi)
                af[mi] = *(const s8v*)(sAl + (wm * 64 + mi * 16 + (lane & 15)) * 64 + krow);
#pragma unroll
            for (int ni = 0; ni < 4; ++ni)
                bfr[ni] = *(const s8v*)(sBl + (wn * 64 + ni * 16 + (lane & 15)) * 64 + krow);
#pragma unroll
            for (int mi = 0; mi < 4; ++mi)
#pragma unroll
                for (int ni = 0; ni < 4; ++ni)
                    acc[mi][ni] = __builtin_amdgcn_mfma_f32_16x16x32_bf16(
                        af[mi], bfr[ni], acc[mi][ni], 0, 0, 0);
        }
        __syncthreads();
    }

    long m0 = (long)bm * 128 + wm * 64;
    long n0 = (long)bn * 128 + wn * 64;
#pragma unroll
    for (int mi = 0; mi < 4; ++mi)
#pragma unroll
        for (int ni = 0; ni < 4; ++ni)
#pragma unroll
            for (int r = 0; r < 4; ++r) {
                long gm = m0 + mi * 16 + (lane >> 4) * 4 + r;
                long gn = n0 + ni * 16 + (lane & 15);
                float v = acc[mi][ni][r];
                if constexpr (HAS_BIAS) v += bias[sBias * bz + gn];
                if constexpr (ACT == 1) v = (v >= 0.f) ? v : 0.01f * v;
                if constexpr (ACT == 2) v = fmaxf(v, 0.f);
                if constexpr (OUTF == 0) {
                    ((bf16*)out)[(long)bz * sO + gm * Nn + gn] = f2bf(v);
                } else if constexpr (OUTF == 1) {
                    ((float*)out)[(long)bz * sO + gm * Nn + gn] = v;
                } else if constexpr (OUTF == 2) {
                    if (gn < 64) {
                        ((float*)out)[gm * 64 + gn] = v + bias[gn];
                    } else {
                        float w = v + bias2[gn - 64];
                        w = fminf(fmaxf(w, -20.f), 2.f);
                        ((float*)out2)[gm * 64 + (gn - 64)] = w;
                    }
                } else {  // OUTF == 3: keys (cols<512) / vals (cols>=512, leaky+bv)
                    if (gn < 512) {
                        ((bf16*)out)[gm * 512 + gn] = f2bf(v);
                    } else {
                        float w = v + bias[gn - 512];
                        w = (w >= 0.f) ? w : 0.01f * w;
                        ((bf16*)out2)[gm * 512 + (gn - 512)] = f2bf(w);
                    }
                }
            }
}

// ---------------------------------------------------------------------------
// Attention: one wave per (b, a); lane = d. 8-way softmax over encoders.
// keys/vals: [E][Bc][512] bf16 (chunk-local). sel: [B][512] f32.
// Writes actor_in f32 (d_out) and bf16 copy for actor GEMM.
// ---------------------------------------------------------------------------
__global__ __launch_bounds__(256) void attn_kernel(
    const float* __restrict__ sel, const bf16* __restrict__ keys,
    const bf16* __restrict__ vals, float* __restrict__ actor_f32,
    bf16* __restrict__ attn_bf, int Bc, int b0) {
    int g = blockIdx.x * 4 + (threadIdx.x >> 6);
    int lane = threadIdx.x & 63;
    int bl = g >> 3, a = g & 7;
    if (bl >= Bc) return;
    long bg = (long)b0 + bl;
    float sv = sel[bg * 512 + a * 64 + lane];
    float logit[8], vv[8];
#pragma unroll
    for (int e = 0; e < 8; ++e) {
        long off = ((long)e * Bc + bl) * 512 + a * 64 + lane;
        float kv = bf2f(keys[off]);
        vv[e] = bf2f(vals[off]);
        float p = sv * kv;
#pragma unroll
        for (int m = 32; m; m >>= 1) p += __shfl_xor(p, m);
        logit[e] = p * 0.125f;  // 1/sqrt(d)
    }
    float mx = logit[0];
#pragma unroll
    for (int e = 1; e < 8; ++e) mx = fmaxf(mx, logit[e]);
    float ssum = 0.f, w[8];
#pragma unroll
    for (int e = 0; e < 8; ++e) { w[e] = __expf(logit[e] - mx); ssum += w[e]; }
    float inv = 1.f / ssum;
    float at = 0.f;
#pragma unroll
    for (int e = 0; e < 8; ++e) at += vv[e] * (w[e] * inv);
    actor_f32[bg * 512 + a * 64 + lane] = at;
    attn_bf[bg * 512 + a * 64 + lane] = f2bf(at);
}

// ---------------------------------------------------------------------------
extern "C" void kernel_launch(void* const* d_in, const int* in_sizes, int n_in,
                              void* d_out, int out_size, void* d_ws, size_t ws_size,
                              hipStream_t stream) {
    (void)in_sizes; (void)n_in; (void)out_size;
    const float* states      = (const float*)d_in[0];
    const float* pre_actions = (const float*)d_in[1];
    const float* W_enc       = (const float*)d_in[2];
    const float* b_enc       = (const float*)d_in[3];
    const float* W_pre       = (const float*)d_in[4];
    const float* b_pre       = (const float*)d_in[5];
    const float* Wk          = (const float*)d_in[6];
    const float* Wsel        = (const float*)d_in[7];
    const float* Wv          = (const float*)d_in[8];
    const float* bv          = (const float*)d_in[9];
    const float* W_actor     = (const float*)d_in[10];
    const float* b_actor     = (const float*)d_in[11];
    const float* W_mean      = (const float*)d_in[12];
    const float* b_mean      = (const float*)d_in[13];
    const float* W_logstd    = (const float*)d_in[14];
    const float* b_logstd    = (const float*)d_in[15];

    char* ws = (char*)d_ws;
    size_t off = 0;
    auto alloc = [&](size_t bytes) -> void* {
        void* p = ws + off;
        off = (off + bytes + 255) & ~(size_t)255;
        return p;
    };
    float* mu_rstd = (float*)alloc((size_t)E_ * 64 * 2 * 4);
    float* bnpart  = (float*)alloc((size_t)E_ * 64 * 64 * 2 * 4);
    bf16* WencfT   = (bf16*)alloc((size_t)E_ * 512 * 64 * 2);
    float* bencf   = (float*)alloc((size_t)E_ * 512 * 4);
    bf16* WpreT    = (bf16*)alloc((size_t)512 * 512 * 2);
    bf16* WselT    = (bf16*)alloc((size_t)512 * 512 * 2);
    bf16* WkvT     = (bf16*)alloc((size_t)1024 * 512 * 2);
    bf16* WactorT  = (bf16*)alloc((size_t)512 * 512 * 2);
    bf16* WmlT     = (bf16*)alloc((size_t)128 * 512 * 2);
    bf16* pa_bf    = (bf16*)alloc((size_t)B_ * 512 * 2);   // aliased later as p_attn
    bf16* p_pre    = (bf16*)alloc((size_t)B_ * 512 * 2);   // aliased later as p_x
    float* p_sel   = (float*)alloc((size_t)B_ * 512 * 4);
    bf16* p_attn = pa_bf;   // pre_actions bf16 dead after K_pre
    bf16* p_x    = p_pre;   // pre dead after K_sel

    // choose chunking over B for the big [E,Bc,*] intermediates
    size_t remaining = (ws_size > off) ? ws_size - off : 0;
    int NC = 32;
    const int ncs[6] = {1, 2, 4, 8, 16, 32};
    for (int t = 0; t < 6; ++t) {
        size_t Bc = (size_t)B_ / ncs[t];
        if (Bc * 25600 + 4096 <= remaining) { NC = ncs[t]; break; }
    }
    const int Bc = B_ / NC;
    bf16* c_sbf  = (bf16*)alloc((size_t)E_ * Bc * 64 * 2);
    bf16* c_encs = (bf16*)alloc((size_t)E_ * Bc * 512 * 2);
    bf16* c_keys = (bf16*)alloc((size_t)E_ * Bc * 512 * 2);
    bf16* c_vals = (bf16*)alloc((size_t)E_ * Bc * 512 * 2);

    // --- prep ---
    cvt4_batched<<<dim3((B_ * 512 / 4 + 255) / 256, 1, 1), 256, 0, stream>>>(
        pre_actions, pa_bf, 0, 0, B_ * 512 / 4);
    packT512<<<1024, 256, 0, stream>>>(W_pre, WpreT);
    packT512<<<1024, 256, 0, stream>>>(W_actor, WactorT);
    packHead<<<1024, 256, 0, stream>>>(Wsel, WselT);
    packHead<<<1024, 256, 0, stream>>>(Wk, WkvT);
    packHead<<<1024, 256, 0, stream>>>(Wv, WkvT + 512 * 512);
    packML<<<256, 256, 0, stream>>>(W_mean, W_logstd, WmlT);
    bnPart<<<512, 256, 0, stream>>>(states, bnpart);
    bnFin<<<2, 256, 0, stream>>>(bnpart, mu_rstd);
    foldEnc<<<16, 256, 0, stream>>>(W_enc, b_enc, mu_rstd, WencfT, bencf);

    // --- pre / sel (full B) ---
    gemm_bt<1, 0, true><<<dim3(B_ / 128, 4, 1), 256, 0, stream>>>(
        pa_bf, WpreT, b_pre, nullptr, p_pre, nullptr, B_, 512, 512, 0, 0, 0, 0);
    gemm_bt<0, 1, false><<<dim3(B_ / 128, 4, 1), 256, 0, stream>>>(
        p_pre, WselT, nullptr, nullptr, p_sel, nullptr, B_, 512, 512, 0, 0, 0, 0);

    // --- chunked encoder -> keys/vals -> attention ---
    float* actor_out = (float*)d_out + 2L * B_ * 64;
    for (int c = 0; c < NC; ++c) {
        int b0 = c * Bc;
        cvt4_batched<<<dim3((Bc * 64 / 4 + 255) / 256, 1, E_), 256, 0, stream>>>(
            states + (long)b0 * 64, c_sbf, (long)B_ * 64, (long)Bc * 64, Bc * 64 / 4);
        gemm_bt<1, 0, true><<<dim3(Bc / 128, 4, E_), 256, 0, stream>>>(
            c_sbf, WencfT, bencf, nullptr, c_encs, nullptr, Bc, 512, 64,
            (long)Bc * 64, (long)512 * 64, 512, (long)Bc * 512);
        gemm_bt<0, 3, false><<<dim3(E_ * Bc / 128, 8, 1), 256, 0, stream>>>(
            c_encs, WkvT, bv, nullptr, c_keys, c_vals, E_ * Bc, 1024, 512, 0, 0, 0, 0);
        attn_kernel<<<Bc * 8 / 4, 256, 0, stream>>>(
            p_sel, c_keys, c_vals, actor_out, p_attn, Bc, b0);
    }

    // --- actor + heads ---
    gemm_bt<2, 0, true><<<dim3(B_ / 128, 4, 1), 256, 0, stream>>>(
        p_attn, WactorT, b_actor, nullptr, p_x, nullptr, B_, 512, 512, 0, 0, 0, 0);
    gemm_bt<0, 2, false><<<dim3(B_ / 128, 1, 1), 256, 0, stream>>>(
        p_x, WmlT, b_mean, b_logstd, (float*)d_out, (float*)d_out + (long)B_ * 64,
        B_, 128, 512, 0, 0, 0, 0);
}

// Round 2
// 630.815 us; speedup vs baseline: 1.0987x; 1.0987x over previous
//
#include <hip/hip_runtime.h>
#include <hip/hip_bf16.h>
#include <stdint.h>

#define E_ 8
#define B_ 16384
#define N_ 64
#define H_ 512
#define A_ 8
#define D_ 64

typedef __hip_bfloat16 bf16;
typedef __attribute__((ext_vector_type(8))) short s8v;     // 8 x bf16 (4 VGPRs)
typedef __attribute__((ext_vector_type(4))) float f4v;     // MFMA accum

__device__ __forceinline__ float bf2f(bf16 v) { return __bfloat162float(v); }
__device__ __forceinline__ bf16 f2bf(float v) { return __float2bfloat16(v); }
__device__ __forceinline__ short f2bfs(float v) {
    bf16 b = f2bf(v); short s; __builtin_memcpy(&s, &b, 2); return s;
}
__device__ __forceinline__ float bfs2f(short s) {
    bf16 b; __builtin_memcpy(&b, &s, 2); return bf2f(b);
}

__device__ __forceinline__ void async_load16(const void* g, void* l) {
    __builtin_amdgcn_global_load_lds(
        (const __attribute__((address_space(1))) void*)g,
        (__attribute__((address_space(3))) void*)l, 16, 0, 0);
}

// Swizzled LDS short-offset for a row-major [128][64]-short tile:
// slot (row, g) holds global K-group (g ^ (row&7)).  krow is a multiple of 8.
__device__ __forceinline__ int swz_off(int row, int krow) {
    return row * 64 + (((krow >> 3) ^ (row & 7)) << 3);
}

// ---------------------------------------------------------------------------
// BatchNorm statistics
// ---------------------------------------------------------------------------
__global__ __launch_bounds__(256) void bnPart(const float* __restrict__ states,
                                              float* __restrict__ part) {
    int blk = blockIdx.x;
    int e = blk >> 6, sl = blk & 63;
    int tid = threadIdx.x, n = tid & 63, rg = tid >> 6;
    const float* base = states + ((long)e * B_ + (long)sl * 256) * 64;
    float s1 = 0.f, s2 = 0.f;
    for (int i = 0; i < 64; ++i) {
        float v = base[(rg + i * 4) * 64 + n];
        s1 += v; s2 += v * v;
    }
    __shared__ float sh[2][4][64];
    sh[0][rg][n] = s1; sh[1][rg][n] = s2;
    __syncthreads();
    if (tid < 64) {
        float t1 = sh[0][0][n] + sh[0][1][n] + sh[0][2][n] + sh[0][3][n];
        float t2 = sh[1][0][n] + sh[1][1][n] + sh[1][2][n] + sh[1][3][n];
        part[((long)blk * 64 + n) * 2 + 0] = t1;
        part[((long)blk * 64 + n) * 2 + 1] = t2;
    }
}

__global__ void bnFin(const float* __restrict__ part, float* __restrict__ mu_rstd) {
    int idx = blockIdx.x * blockDim.x + threadIdx.x;  // e*64+n
    if (idx >= E_ * 64) return;
    int e = idx >> 6, n = idx & 63;
    float s1 = 0.f, s2 = 0.f;
    for (int sl = 0; sl < 64; ++sl) {
        s1 += part[(((long)e * 64 + sl) * 64 + n) * 2 + 0];
        s2 += part[(((long)e * 64 + sl) * 64 + n) * 2 + 1];
    }
    float mu = s1 / (float)B_;
    float var = s2 / (float)B_ - mu * mu;
    mu_rstd[idx * 2 + 0] = mu;
    mu_rstd[idx * 2 + 1] = rsqrtf(var + 1e-5f);
}

// ---------------------------------------------------------------------------
// Weight prep
// ---------------------------------------------------------------------------
__global__ void packT512(const float* __restrict__ in, bf16* __restrict__ out) {
    int idx = blockIdx.x * 256 + threadIdx.x;  // 512*512
    int n = idx >> 9, k = idx & 511;
    out[idx] = f2bf(in[k * 512 + n]);
}

// Wsel: [A,H,d] -> WT[(a*64+dd)*512 + h]
__global__ void packHead(const float* __restrict__ in, bf16* __restrict__ out) {
    int idx = blockIdx.x * 256 + threadIdx.x;  // 512*512
    int n = idx >> 9, h = idx & 511;
    int a = n >> 6, dd = n & 63;
    out[idx] = f2bf(in[((long)a * 512 + h) * 64 + dd]);
}

// Wk/Wv head-interleaved: row n = a*128 + j; j<64 -> Wk[a][:,j], else Wv[a][:,j-64]
__global__ void packHeadKV(const float* __restrict__ Wk, const float* __restrict__ Wv,
                           bf16* __restrict__ out) {
    int idx = blockIdx.x * 256 + threadIdx.x;  // 1024*512
    int n = idx >> 9, h = idx & 511;
    int a = n >> 7, j = n & 127;
    const float* src = (j < 64) ? Wk : Wv;
    out[idx] = f2bf(src[((long)a * 512 + h) * 64 + (j & 63)]);
}

// WmlT [128][512]: rows 0..63 = W_mean^T, rows 64..127 = W_logstd^T
__global__ void packML(const float* __restrict__ wm, const float* __restrict__ wl,
                       bf16* __restrict__ out) {
    int idx = blockIdx.x * 256 + threadIdx.x;  // 128*512
    int n = idx >> 9, k = idx & 511;
    float v = (n < 64) ? wm[k * 64 + n] : wl[k * 64 + (n - 64)];
    out[idx] = f2bf(v);
}

// Fold BN into encoder weight
__global__ void foldEnc(const float* __restrict__ W_enc, const float* __restrict__ b_enc,
                        const float* __restrict__ mu_rstd,
                        bf16* __restrict__ WencfT, float* __restrict__ bencf) {
    int idx = blockIdx.x * 256 + threadIdx.x;  // E*H = 4096
    int e = idx >> 9, h = idx & 511;
    float acc = b_enc[e * 512 + h];
    for (int n = 0; n < 64; ++n) {
        float mu = mu_rstd[(e * 64 + n) * 2 + 0];
        float rs = mu_rstd[(e * 64 + n) * 2 + 1];
        float w = W_enc[((long)e * 64 + n) * 512 + h];
        WencfT[((long)e * 512 + h) * 64 + n] = f2bf(w * rs);
        acc -= mu * rs * w;
    }
    bencf[e * 512 + h] = acc;
}

// f32 -> bf16, float4-vectorized, batched via grid.z
__global__ void cvt4_batched(const float* __restrict__ in, bf16* __restrict__ out,
                             long inStrideZ, long outStrideZ, int n4) {
    int i = blockIdx.x * blockDim.x + threadIdx.x;
    if (i >= n4) return;
    const float4* ip = (const float4*)(in + (long)blockIdx.z * inStrideZ);
    float4 v = ip[i];
    bf16 o[4] = {f2bf(v.x), f2bf(v.y), f2bf(v.z), f2bf(v.w)};
    __builtin_memcpy(out + (long)blockIdx.z * outStrideZ + (long)i * 4, o, 8);
}

// ---------------------------------------------------------------------------
// Generic MFMA GEMM with XOR-swizzled LDS (conflict-free ds_read_b128):
// C[M][Nn] = act(A[M][K] * BT[Nn][K]^T + bias)
// Grid: x = rowblocks << CB (bm = x>>CB, bn = x & mask, y-fastest for L2 reuse)
// OUTF: 0 bf16 out; 1 f32 out; 2 final mean/logstd split; 4 encs [b][e][512]
// ---------------------------------------------------------------------------
template <int ACT, int OUTF, bool HAS_BIAS, int CB>
__global__ __launch_bounds__(256) void gemm_bt(
    const bf16* __restrict__ Ag, const bf16* __restrict__ Bg,
    const float* __restrict__ bias, const float* __restrict__ bias2,
    void* __restrict__ out, void* __restrict__ out2,
    int M, int Nn, int K, long sA, long sB, long sBias, long sO) {
    const int tid = threadIdx.x, lane = tid & 63, wid = tid >> 6;
    const int wm = wid >> 1, wn = wid & 1;
    const int bm = blockIdx.x >> CB, bn = blockIdx.x & ((1 << CB) - 1);
    const int bz = blockIdx.z;
    const bf16* Aptr = Ag + (long)bz * sA + (long)bm * 128 * K;
    const bf16* Bptr = Bg + (long)bz * sB + (long)bn * 128 * K;

    __shared__ __align__(16) short sAl[128 * 64];
    __shared__ __align__(16) short sBl[128 * 64];

    // swizzled staging source: lane covers slot (r = base8*8 + lane>>3, g = lane&7)
    // holding global K-group (g ^ (r&7)); r&7 == lane>>3.
    const int srow = lane >> 3;
    const int scol = (((lane & 7) ^ srow) << 3);

    f4v acc[4][4];
#pragma unroll
    for (int i = 0; i < 4; ++i)
#pragma unroll
        for (int j = 0; j < 4; ++j) acc[i][j] = f4v{0.f, 0.f, 0.f, 0.f};

    for (int k0 = 0; k0 < K; k0 += 64) {
#pragma unroll
        for (int i = 0; i < 4; ++i) {
            int r = (wid * 4 + i) * 8 + srow;
            async_load16(Aptr + (long)r * K + k0 + scol, (char*)sAl + (wid * 4 + i) * 1024);
            async_load16(Bptr + (long)r * K + k0 + scol, (char*)sBl + (wid * 4 + i) * 1024);
        }
        __syncthreads();
#pragma unroll
        for (int kk = 0; kk < 64; kk += 32) {
            int krow = kk + (lane >> 4) * 8;
            s8v af[4], bfr[4];
#pragma unroll
            for (int mi = 0; mi < 4; ++mi)
                af[mi] = *(const s8v*)(sAl + swz_off(wm * 64 + mi * 16 + (lane & 15), krow));
#pragma unroll
            for (int ni = 0; ni < 4; ++ni)
                bfr[ni] = *(const s8v*)(sBl + swz_off(wn * 64 + ni * 16 + (lane & 15), krow));
#pragma unroll
            for (int mi = 0; mi < 4; ++mi)
#pragma unroll
                for (int ni = 0; ni < 4; ++ni)
                    acc[mi][ni] = __builtin_amdgcn_mfma_f32_16x16x32_bf16(
                        af[mi], bfr[ni], acc[mi][ni], 0, 0, 0);
        }
        __syncthreads();
    }

    long m0 = (long)bm * 128 + wm * 64;
    long n0 = (long)bn * 128 + wn * 64;
#pragma unroll
    for (int mi = 0; mi < 4; ++mi)
#pragma unroll
        for (int ni = 0; ni < 4; ++ni)
#pragma unroll
            for (int r = 0; r < 4; ++r) {
                long gm = m0 + mi * 16 + (lane >> 4) * 4 + r;
                long gn = n0 + ni * 16 + (lane & 15);
                float v = acc[mi][ni][r];
                if constexpr (HAS_BIAS) v += bias[sBias * bz + gn];
                if constexpr (ACT == 1) v = (v >= 0.f) ? v : 0.01f * v;
                if constexpr (ACT == 2) v = fmaxf(v, 0.f);
                if constexpr (OUTF == 0) {
                    ((bf16*)out)[(long)bz * sO + gm * Nn + gn] = f2bf(v);
                } else if constexpr (OUTF == 1) {
                    ((float*)out)[(long)bz * sO + gm * Nn + gn] = v;
                } else if constexpr (OUTF == 2) {
                    if (gn < 64) {
                        ((float*)out)[gm * 64 + gn] = v + bias[gn];
                    } else {
                        float w = v + bias2[gn - 64];
                        w = fminf(fmaxf(w, -20.f), 2.f);
                        ((float*)out2)[gm * 64 + (gn - 64)] = w;
                    }
                } else {  // OUTF == 4: encs reordered [b][E][512], bz = e
                    ((bf16*)out)[(gm * E_ + bz) * 512 + gn] = f2bf(v);
                }
            }
}

// ---------------------------------------------------------------------------
// Fused keys/vals GEMM + softmax-attention.
// A = encs [Bc*E][512] bf16, rows ordered b-major-e (row = b*8 + e, chunk-local).
// B = WkvaT [1024][512]: row a*128+j -> (j<64 ? Wk : Wv) head a.
// Block (bm, a): 128 rows (16 b x 8 e) x 128 cols (keys|vals of head a).
// Epilogue: tile -> LDS (stride 132, conflict-free), softmax over e, write
// actor_in (f32 to d_out region, bf16 to p_attn). Keys/vals never hit HBM.
// ---------------------------------------------------------------------------
__global__ __launch_bounds__(256) void kv_attn(
    const bf16* __restrict__ Ag, const bf16* __restrict__ Bg,
    const float* __restrict__ bv, const float* __restrict__ sel,
    float* __restrict__ actor_f32, bf16* __restrict__ attn_bf, int b0) {
    const int tid = threadIdx.x, lane = tid & 63, wid = tid >> 6;
    const int wm = wid >> 1, wn = wid & 1;
    const int bm = blockIdx.x >> 3, a = blockIdx.x & 7;
    const bf16* Aptr = Ag + (long)bm * 128 * 512;
    const bf16* Bptr = Bg + (long)a * 128 * 512;

    __shared__ __align__(16) short sm[128 * 132];  // staging (2x8192) & C-tile overlay
    short* sAl = sm;
    short* sBl = sm + 128 * 64;

    // prefetch selector values for this block's 4 b's per wave
    const long bgBase = (long)b0 + (long)bm * 16;
    float sv[4];
#pragma unroll
    for (int t = 0; t < 4; ++t)
        sv[t] = sel[(bgBase + wid * 4 + t) * 512 + a * 64 + lane];

    const int srow = lane >> 3;
    const int scol = (((lane & 7) ^ srow) << 3);

    f4v acc[4][4];
#pragma unroll
    for (int i = 0; i < 4; ++i)
#pragma unroll
        for (int j = 0; j < 4; ++j) acc[i][j] = f4v{0.f, 0.f, 0.f, 0.f};

    for (int k0 = 0; k0 < 512; k0 += 64) {
#pragma unroll
        for (int i = 0; i < 4; ++i) {
            int r = (wid * 4 + i) * 8 + srow;
            async_load16(Aptr + (long)r * 512 + k0 + scol, (char*)sAl + (wid * 4 + i) * 1024);
            async_load16(Bptr + (long)r * 512 + k0 + scol, (char*)sBl + (wid * 4 + i) * 1024);
        }
        __syncthreads();
#pragma unroll
        for (int kk = 0; kk < 64; kk += 32) {
            int krow = kk + (lane >> 4) * 8;
            s8v af[4], bfr[4];
#pragma unroll
            for (int mi = 0; mi < 4; ++mi)
                af[mi] = *(const s8v*)(sAl + swz_off(wm * 64 + mi * 16 + (lane & 15), krow));
#pragma unroll
            for (int ni = 0; ni < 4; ++ni)
                bfr[ni] = *(const s8v*)(sBl + swz_off(wn * 64 + ni * 16 + (lane & 15), krow));
#pragma unroll
            for (int mi = 0; mi < 4; ++mi)
#pragma unroll
                for (int ni = 0; ni < 4; ++ni)
                    acc[mi][ni] = __builtin_amdgcn_mfma_f32_16x16x32_bf16(
                        af[mi], bfr[ni], acc[mi][ni], 0, 0, 0);
        }
        __syncthreads();
    }

    // ---- epilogue: C tile -> LDS (bf16, stride 132), vals get bias+leaky ----
    const int quad = lane >> 4, cl = lane & 15;
#pragma unroll
    for (int mi = 0; mi < 4; ++mi)
#pragma unroll
        for (int ni = 0; ni < 4; ++ni)
#pragma unroll
            for (int r = 0; r < 4; ++r) {
                int row = wm * 64 + mi * 16 + quad * 4 + r;
                int col = wn * 64 + ni * 16 + cl;
                float v = acc[mi][ni][r];
                if (wn == 1) {  // vals half
                    v += bv[a * 64 + (col - 64)];
                    v = (v >= 0.f) ? v : 0.01f * v;
                }
                sm[row * 132 + col] = f2bfs(v);
            }
    __syncthreads();

    // ---- attention: each wave handles 4 b's; lane = d ----
#pragma unroll
    for (int t = 0; t < 4; ++t) {
        int lb = wid * 4 + t;
        float lg[8], vv[8];
#pragma unroll
        for (int e = 0; e < 8; ++e) {
            int row = lb * 8 + e;
            float kv = bfs2f(sm[row * 132 + lane]);
            vv[e] = bfs2f(sm[row * 132 + 64 + lane]);
            float p = sv[t] * kv;
#pragma unroll
            for (int m = 32; m; m >>= 1) p += __shfl_xor(p, m);
            lg[e] = p * 0.125f;  // 1/sqrt(d)
        }
        float mx = lg[0];
#pragma unroll
        for (int e = 1; e < 8; ++e) mx = fmaxf(mx, lg[e]);
        float ssum = 0.f, w[8];
#pragma unroll
        for (int e = 0; e < 8; ++e) { w[e] = __expf(lg[e] - mx); ssum += w[e]; }
        float inv = 1.f / ssum;
        float at = 0.f;
#pragma unroll
        for (int e = 0; e < 8; ++e) at += vv[e] * (w[e] * inv);
        long o = (bgBase + lb) * 512 + a * 64 + lane;
        actor_f32[o] = at;
        attn_bf[o] = f2bf(at);
    }
}

// ---------------------------------------------------------------------------
extern "C" void kernel_launch(void* const* d_in, const int* in_sizes, int n_in,
                              void* d_out, int out_size, void* d_ws, size_t ws_size,
                              hipStream_t stream) {
    (void)in_sizes; (void)n_in; (void)out_size;
    const float* states      = (const float*)d_in[0];
    const float* pre_actions = (const float*)d_in[1];
    const float* W_enc       = (const float*)d_in[2];
    const float* b_enc       = (const float*)d_in[3];
    const float* W_pre       = (const float*)d_in[4];
    const float* b_pre       = (const float*)d_in[5];
    const float* Wk          = (const float*)d_in[6];
    const float* Wsel        = (const float*)d_in[7];
    const float* Wv          = (const float*)d_in[8];
    const float* bv          = (const float*)d_in[9];
    const float* W_actor     = (const float*)d_in[10];
    const float* b_actor     = (const float*)d_in[11];
    const float* W_mean      = (const float*)d_in[12];
    const float* b_mean      = (const float*)d_in[13];
    const float* W_logstd    = (const float*)d_in[14];
    const float* b_logstd    = (const float*)d_in[15];

    char* ws = (char*)d_ws;
    size_t off = 0;
    auto alloc = [&](size_t bytes) -> void* {
        void* p = ws + off;
        off = (off + bytes + 255) & ~(size_t)255;
        return p;
    };
    float* mu_rstd = (float*)alloc((size_t)E_ * 64 * 2 * 4);
    float* bnpart  = (float*)alloc((size_t)E_ * 64 * 64 * 2 * 4);
    bf16* WencfT   = (bf16*)alloc((size_t)E_ * 512 * 64 * 2);
    float* bencf   = (float*)alloc((size_t)E_ * 512 * 4);
    bf16* WpreT    = (bf16*)alloc((size_t)512 * 512 * 2);
    bf16* WselT    = (bf16*)alloc((size_t)512 * 512 * 2);
    bf16* WkvaT    = (bf16*)alloc((size_t)1024 * 512 * 2);
    bf16* WactorT  = (bf16*)alloc((size_t)512 * 512 * 2);
    bf16* WmlT     = (bf16*)alloc((size_t)128 * 512 * 2);
    bf16* pa_bf    = (bf16*)alloc((size_t)B_ * 512 * 2);   // aliased later as p_attn
    bf16* p_pre    = (bf16*)alloc((size_t)B_ * 512 * 2);   // aliased later as p_x
    float* p_sel   = (float*)alloc((size_t)B_ * 512 * 4);
    bf16* p_attn = pa_bf;   // pre_actions bf16 dead after pre GEMM
    bf16* p_x    = p_pre;   // pre dead after sel GEMM

    // chunk over B: per-chunk bytes = Bc*(E*64*2) + Bc*(E*512*2) = Bc*9216
    size_t remaining = (ws_size > off) ? ws_size - off : 0;
    int Bc = B_;
    while (Bc > 128 && (size_t)Bc * 9216 + 4096 > remaining) Bc >>= 1;
    const int NC = B_ / Bc;
    bf16* c_sbf  = (bf16*)alloc((size_t)E_ * Bc * 64 * 2);
    bf16* c_encs = (bf16*)alloc((size_t)E_ * Bc * 512 * 2);  // [b][e][512]

    // --- prep ---
    cvt4_batched<<<dim3((B_ * 512 / 4 + 255) / 256, 1, 1), 256, 0, stream>>>(
        pre_actions, pa_bf, 0, 0, B_ * 512 / 4);
    packT512<<<1024, 256, 0, stream>>>(W_pre, WpreT);
    packT512<<<1024, 256, 0, stream>>>(W_actor, WactorT);
    packHead<<<1024, 256, 0, stream>>>(Wsel, WselT);
    packHeadKV<<<2048, 256, 0, stream>>>(Wk, Wv, WkvaT);
    packML<<<256, 256, 0, stream>>>(W_mean, W_logstd, WmlT);
    bnPart<<<512, 256, 0, stream>>>(states, bnpart);
    bnFin<<<2, 256, 0, stream>>>(bnpart, mu_rstd);
    foldEnc<<<16, 256, 0, stream>>>(W_enc, b_enc, mu_rstd, WencfT, bencf);

    // --- pre / sel (full B) ---
    gemm_bt<1, 0, true, 2><<<dim3((B_ / 128) << 2, 1, 1), 256, 0, stream>>>(
        pa_bf, WpreT, b_pre, nullptr, p_pre, nullptr, B_, 512, 512, 0, 0, 0, 0);
    gemm_bt<0, 1, false, 2><<<dim3((B_ / 128) << 2, 1, 1), 256, 0, stream>>>(
        p_pre, WselT, nullptr, nullptr, p_sel, nullptr, B_, 512, 512, 0, 0, 0, 0);

    // --- chunked: states->bf16, encoder GEMM ([b][e][512]), fused kv+attn ---
    float* actor_out = (float*)d_out + 2L * B_ * 64;
    for (int c = 0; c < NC; ++c) {
        int b0 = c * Bc;
        cvt4_batched<<<dim3((Bc * 64 / 4 + 255) / 256, 1, E_), 256, 0, stream>>>(
            states + (long)b0 * 64, c_sbf, (long)B_ * 64, (long)Bc * 64, Bc * 64 / 4);
        gemm_bt<1, 4, true, 2><<<dim3((Bc / 128) << 2, 1, E_), 256, 0, stream>>>(
            c_sbf, WencfT, bencf, nullptr, c_encs, nullptr, Bc, 512, 64,
            (long)Bc * 64, (long)512 * 64, 512, 0);
        kv_attn<<<dim3((Bc / 16) * 8, 1, 1), 256, 0, stream>>>(
            c_encs, WkvaT, bv, p_sel, actor_out, p_attn, b0);
    }

    // --- actor + heads ---
    gemm_bt<2, 0, true, 2><<<dim3((B_ / 128) << 2, 1, 1), 256, 0, stream>>>(
        p_attn, WactorT, b_actor, nullptr, p_x, nullptr, B_, 512, 512, 0, 0, 0, 0);
    gemm_bt<0, 2, false, 0><<<dim3(B_ / 128, 1, 1), 256, 0, stream>>>(
        p_x, WmlT, b_mean, b_logstd, (float*)d_out, (float*)d_out + (long)B_ * 64,
        B_, 128, 512, 0, 0, 0, 0);
}

// Round 4
// 618.596 us; speedup vs baseline: 1.1204x; 1.0198x over previous
//
#include <hip/hip_runtime.h>
#include <hip/hip_bf16.h>
#include <stdint.h>

#define E_ 8
#define B_ 16384
#define N_ 64
#define H_ 512
#define A_ 8
#define D_ 64

typedef __hip_bfloat16 bf16;
typedef __attribute__((ext_vector_type(8))) short s8v;     // 8 x bf16 (4 VGPRs)
typedef __attribute__((ext_vector_type(4))) float f4v;     // MFMA accum

__device__ __forceinline__ float bf2f(bf16 v) { return __bfloat162float(v); }
__device__ __forceinline__ bf16 f2bf(float v) { return __float2bfloat16(v); }
__device__ __forceinline__ short f2bfs(float v) {
    bf16 b = f2bf(v); short s; __builtin_memcpy(&s, &b, 2); return s;
}
__device__ __forceinline__ float bfs2f(short s) {
    bf16 b; __builtin_memcpy(&b, &s, 2); return bf2f(b);
}

__device__ __forceinline__ void async_load16(const void* g, void* l) {
    __builtin_amdgcn_global_load_lds(
        (const __attribute__((address_space(1))) void*)g,
        (__attribute__((address_space(3))) void*)l, 16, 0, 0);
}

// Swizzled LDS short-offset for a row-major [128][64]-short tile:
// slot (row, g) holds global K-group (g ^ (row&7)).  krow is a multiple of 8.
__device__ __forceinline__ int swz_off(int row, int krow) {
    return row * 64 + (((krow >> 3) ^ (row & 7)) << 3);
}

// XCD-aware block mapping: blocks sharing an A-panel (all nBn bn's of one bm)
// get linear ids differing by 8 -> same XCD (id%8), temporally adjacent.
template <int CB>
__device__ __forceinline__ void xcd_map(int x, int nBm, int& bm, int& bn) {
    if ((nBm & 7) == 0) {
        int j = x & 7, s = x >> 3;
        bn = s & ((1 << CB) - 1);
        bm = ((s >> CB) << 3) | j;
    } else {
        bm = x >> CB;
        bn = x & ((1 << CB) - 1);
    }
}

// ---------------------------------------------------------------------------
// BatchNorm statistics
// ---------------------------------------------------------------------------
__global__ __launch_bounds__(256) void bnPart(const float* __restrict__ states,
                                              float* __restrict__ part) {
    int blk = blockIdx.x;
    int e = blk >> 6, sl = blk & 63;
    int tid = threadIdx.x, n = tid & 63, rg = tid >> 6;
    const float* base = states + ((long)e * B_ + (long)sl * 256) * 64;
    float s1 = 0.f, s2 = 0.f;
    for (int i = 0; i < 64; ++i) {
        float v = base[(rg + i * 4) * 64 + n];
        s1 += v; s2 += v * v;
    }
    __shared__ float sh[2][4][64];
    sh[0][rg][n] = s1; sh[1][rg][n] = s2;
    __syncthreads();
    if (tid < 64) {
        float t1 = sh[0][0][n] + sh[0][1][n] + sh[0][2][n] + sh[0][3][n];
        float t2 = sh[1][0][n] + sh[1][1][n] + sh[1][2][n] + sh[1][3][n];
        part[((long)blk * 64 + n) * 2 + 0] = t1;
        part[((long)blk * 64 + n) * 2 + 1] = t2;
    }
}

__global__ void bnFin(const float* __restrict__ part, float* __restrict__ mu_rstd) {
    int idx = blockIdx.x * blockDim.x + threadIdx.x;  // e*64+n
    if (idx >= E_ * 64) return;
    int e = idx >> 6, n = idx & 63;
    float s1 = 0.f, s2 = 0.f;
    for (int sl = 0; sl < 64; ++sl) {
        s1 += part[(((long)e * 64 + sl) * 64 + n) * 2 + 0];
        s2 += part[(((long)e * 64 + sl) * 64 + n) * 2 + 1];
    }
    float mu = s1 / (float)B_;
    float var = s2 / (float)B_ - mu * mu;
    mu_rstd[idx * 2 + 0] = mu;
    mu_rstd[idx * 2 + 1] = rsqrtf(var + 1e-5f);
}

// Fold BN into encoder weight
__global__ void foldEnc(const float* __restrict__ W_enc, const float* __restrict__ b_enc,
                        const float* __restrict__ mu_rstd,
                        bf16* __restrict__ WencfT, float* __restrict__ bencf) {
    int idx = blockIdx.x * 256 + threadIdx.x;  // E*H = 4096
    int e = idx >> 9, h = idx & 511;
    float acc = b_enc[e * 512 + h];
    for (int n = 0; n < 64; ++n) {
        float mu = mu_rstd[(e * 64 + n) * 2 + 0];
        float rs = mu_rstd[(e * 64 + n) * 2 + 1];
        float w = W_enc[((long)e * 64 + n) * 512 + h];
        WencfT[((long)e * 512 + h) * 64 + n] = f2bf(w * rs);
        acc -= mu * rs * w;
    }
    bencf[e * 512 + h] = acc;
}

// ---------------------------------------------------------------------------
// All weight packing + pre_actions f32->bf16, fused into one dispatch.
// blocks [0,1024): WpreT      [1024,2048): WactorT   [2048,3072): WselT
//        [3072,5120): WkvaT   [5120,5376): WmlT      [5376,13568): pa_bf
// pa_bf needs B*512/4 = 2097152 float4 = 8192 blocks of 256.  (r3 bug: had 2048)
// ---------------------------------------------------------------------------
__global__ __launch_bounds__(256) void packAll(
    const float* __restrict__ W_pre, const float* __restrict__ W_actor,
    const float* __restrict__ Wsel, const float* __restrict__ Wk,
    const float* __restrict__ Wv, const float* __restrict__ wm,
    const float* __restrict__ wl, const float* __restrict__ pre_actions,
    bf16* __restrict__ WpreT, bf16* __restrict__ WactorT, bf16* __restrict__ WselT,
    bf16* __restrict__ WkvaT, bf16* __restrict__ WmlT, bf16* __restrict__ pa_bf) {
    int bx = blockIdx.x, tid = threadIdx.x;
    if (bx < 2048) {  // WpreT / WactorT: out[n*512+k] = in[k*512+n]
        const float* in = (bx < 1024) ? W_pre : W_actor;
        bf16* out = (bx < 1024) ? WpreT : WactorT;
        int idx = (bx & 1023) * 256 + tid;
        int n = idx >> 9, k = idx & 511;
        out[idx] = f2bf(in[k * 512 + n]);
    } else if (bx < 3072) {  // WselT: [(a*64+dd)*512+h] = Wsel[a][h][dd]
        int idx = (bx - 2048) * 256 + tid;
        int n = idx >> 9, h = idx & 511;
        int a = n >> 6, dd = n & 63;
        WselT[idx] = f2bf(Wsel[((long)a * 512 + h) * 64 + dd]);
    } else if (bx < 5120) {  // WkvaT: row a*128+j -> (j<64?Wk:Wv)[a][:,j&63]
        int idx = (bx - 3072) * 256 + tid;
        int n = idx >> 9, h = idx & 511;
        int a = n >> 7, j = n & 127;
        const float* src = (j < 64) ? Wk : Wv;
        WkvaT[idx] = f2bf(src[((long)a * 512 + h) * 64 + (j & 63)]);
    } else if (bx < 5376) {  // WmlT [128][512]
        int idx = (bx - 5120) * 256 + tid;
        int n = idx >> 9, k = idx & 511;
        float v = (n < 64) ? wm[k * 64 + n] : wl[k * 64 + (n - 64)];
        WmlT[idx] = f2bf(v);
    } else {  // pa_bf: float4 cvt, 8192 blocks cover B*512/4 exactly
        int i = (bx - 5376) * 256 + tid;
        float4 v = ((const float4*)pre_actions)[i];
        bf16 o[4] = {f2bf(v.x), f2bf(v.y), f2bf(v.z), f2bf(v.w)};
        __builtin_memcpy(pa_bf + (long)i * 4, o, 8);
    }
}

// f32 -> bf16, float4-vectorized, batched via grid.z (states chunks)
__global__ void cvt4_batched(const float* __restrict__ in, bf16* __restrict__ out,
                             long inStrideZ, long outStrideZ, int n4) {
    int i = blockIdx.x * blockDim.x + threadIdx.x;
    if (i >= n4) return;
    const float4* ip = (const float4*)(in + (long)blockIdx.z * inStrideZ);
    float4 v = ip[i];
    bf16 o[4] = {f2bf(v.x), f2bf(v.y), f2bf(v.z), f2bf(v.w)};
    __builtin_memcpy(out + (long)blockIdx.z * outStrideZ + (long)i * 4, o, 8);
}

// ---------------------------------------------------------------------------
// Generic MFMA GEMM, XOR-swizzled LDS, XCD-aware block mapping.
// C[M][Nn] = act(A[M][K] * BT[Nn][K]^T + bias)
// OUTF: 0 bf16 out; 1 f32 out; 2 final mean/logstd split; 4 encs [b][e][512]
// ---------------------------------------------------------------------------
template <int ACT, int OUTF, bool HAS_BIAS, int CB>
__global__ __launch_bounds__(256) void gemm_bt(
    const bf16* __restrict__ Ag, const bf16* __restrict__ Bg,
    const float* __restrict__ bias, const float* __restrict__ bias2,
    void* __restrict__ out, void* __restrict__ out2,
    int M, int Nn, int K, long sA, long sB, long sBias, long sO) {
    const int tid = threadIdx.x, lane = tid & 63, wid = tid >> 6;
    const int wm = wid >> 1, wn = wid & 1;
    int bm, bn;
    xcd_map<CB>(blockIdx.x, gridDim.x >> CB, bm, bn);
    const int bz = blockIdx.z;
    const bf16* Aptr = Ag + (long)bz * sA + (long)bm * 128 * K;
    const bf16* Bptr = Bg + (long)bz * sB + (long)bn * 128 * K;

    __shared__ __align__(16) short sAl[128 * 64];
    __shared__ __align__(16) short sBl[128 * 64];

    const int srow = lane >> 3;
    const int scol = (((lane & 7) ^ srow) << 3);

    f4v acc[4][4];
#pragma unroll
    for (int i = 0; i < 4; ++i)
#pragma unroll
        for (int j = 0; j < 4; ++j) acc[i][j] = f4v{0.f, 0.f, 0.f, 0.f};

    for (int k0 = 0; k0 < K; k0 += 64) {
#pragma unroll
        for (int i = 0; i < 4; ++i) {
            int r = (wid * 4 + i) * 8 + srow;
            async_load16(Aptr + (long)r * K + k0 + scol, (char*)sAl + (wid * 4 + i) * 1024);
            async_load16(Bptr + (long)r * K + k0 + scol, (char*)sBl + (wid * 4 + i) * 1024);
        }
        __syncthreads();
#pragma unroll
        for (int kk = 0; kk < 64; kk += 32) {
            int krow = kk + (lane >> 4) * 8;
            s8v af[4], bfr[4];
#pragma unroll
            for (int mi = 0; mi < 4; ++mi)
                af[mi] = *(const s8v*)(sAl + swz_off(wm * 64 + mi * 16 + (lane & 15), krow));
#pragma unroll
            for (int ni = 0; ni < 4; ++ni)
                bfr[ni] = *(const s8v*)(sBl + swz_off(wn * 64 + ni * 16 + (lane & 15), krow));
#pragma unroll
            for (int mi = 0; mi < 4; ++mi)
#pragma unroll
                for (int ni = 0; ni < 4; ++ni)
                    acc[mi][ni] = __builtin_amdgcn_mfma_f32_16x16x32_bf16(
                        af[mi], bfr[ni], acc[mi][ni], 0, 0, 0);
        }
        __syncthreads();
    }

    long m0 = (long)bm * 128 + wm * 64;
    long n0 = (long)bn * 128 + wn * 64;
#pragma unroll
    for (int mi = 0; mi < 4; ++mi)
#pragma unroll
        for (int ni = 0; ni < 4; ++ni)
#pragma unroll
            for (int r = 0; r < 4; ++r) {
                long gm = m0 + mi * 16 + (lane >> 4) * 4 + r;
                long gn = n0 + ni * 16 + (lane & 15);
                float v = acc[mi][ni][r];
                if constexpr (HAS_BIAS) v += bias[sBias * bz + gn];
                if constexpr (ACT == 1) v = (v >= 0.f) ? v : 0.01f * v;
                if constexpr (ACT == 2) v = fmaxf(v, 0.f);
                if constexpr (OUTF == 0) {
                    ((bf16*)out)[(long)bz * sO + gm * Nn + gn] = f2bf(v);
                } else if constexpr (OUTF == 1) {
                    ((float*)out)[(long)bz * sO + gm * Nn + gn] = v;
                } else if constexpr (OUTF == 2) {
                    if (gn < 64) {
                        ((float*)out)[gm * 64 + gn] = v + bias[gn];
                    } else {
                        float w = v + bias2[gn - 64];
                        w = fminf(fmaxf(w, -20.f), 2.f);
                        ((float*)out2)[gm * 64 + (gn - 64)] = w;
                    }
                } else {  // OUTF == 4: encs reordered [b][E][512], bz = e
                    ((bf16*)out)[(gm * E_ + bz) * 512 + gn] = f2bf(v);
                }
            }
}

// ---------------------------------------------------------------------------
// Fused keys/vals GEMM + softmax-attention (XCD-swizzled).
// A = encs [Bc*E][512] bf16 (row = b*8+e). B = WkvaT [1024][512].
// Block (bm, a): 128 rows (16 b x 8 e) x 128 cols (keys|vals of head a).
// ---------------------------------------------------------------------------
__global__ __launch_bounds__(256) void kv_attn(
    const bf16* __restrict__ Ag, const bf16* __restrict__ Bg,
    const float* __restrict__ bv, const float* __restrict__ sel,
    float* __restrict__ actor_f32, bf16* __restrict__ attn_bf, int b0) {
    const int tid = threadIdx.x, lane = tid & 63, wid = tid >> 6;
    const int wm = wid >> 1, wn = wid & 1;
    int bm, a;
    xcd_map<3>(blockIdx.x, gridDim.x >> 3, bm, a);
    const bf16* Aptr = Ag + (long)bm * 128 * 512;
    const bf16* Bptr = Bg + (long)a * 128 * 512;

    __shared__ __align__(16) short sm[128 * 132];  // staging & C-tile overlay
    short* sAl = sm;
    short* sBl = sm + 128 * 64;

    const long bgBase = (long)b0 + (long)bm * 16;
    float sv[4];
#pragma unroll
    for (int t = 0; t < 4; ++t)
        sv[t] = sel[(bgBase + wid * 4 + t) * 512 + a * 64 + lane];

    const int srow = lane >> 3;
    const int scol = (((lane & 7) ^ srow) << 3);

    f4v acc[4][4];
#pragma unroll
    for (int i = 0; i < 4; ++i)
#pragma unroll
        for (int j = 0; j < 4; ++j) acc[i][j] = f4v{0.f, 0.f, 0.f, 0.f};

    for (int k0 = 0; k0 < 512; k0 += 64) {
#pragma unroll
        for (int i = 0; i < 4; ++i) {
            int r = (wid * 4 + i) * 8 + srow;
            async_load16(Aptr + (long)r * 512 + k0 + scol, (char*)sAl + (wid * 4 + i) * 1024);
            async_load16(Bptr + (long)r * 512 + k0 + scol, (char*)sBl + (wid * 4 + i) * 1024);
        }
        __syncthreads();
#pragma unroll
        for (int kk = 0; kk < 64; kk += 32) {
            int krow = kk + (lane >> 4) * 8;
            s8v af[4], bfr[4];
#pragma unroll
            for (int mi = 0; mi < 4; ++mi)
                af[mi] = *(const s8v*)(sAl + swz_off(wm * 64 + mi * 16 + (lane & 15), krow));
#pragma unroll
            for (int ni = 0; ni < 4; ++ni)
                bfr[ni] = *(const s8v*)(sBl + swz_off(wn * 64 + ni * 16 + (lane & 15), krow));
#pragma unroll
            for (int mi = 0; mi < 4; ++mi)
#pragma unroll
                for (int ni = 0; ni < 4; ++ni)
                    acc[mi][ni] = __builtin_amdgcn_mfma_f32_16x16x32_bf16(
                        af[mi], bfr[ni], acc[mi][ni], 0, 0, 0);
        }
        __syncthreads();
    }

    // ---- epilogue: C tile -> LDS (bf16, stride 132), vals get bias+leaky ----
    const int quad = lane >> 4, cl = lane & 15;
#pragma unroll
    for (int mi = 0; mi < 4; ++mi)
#pragma unroll
        for (int ni = 0; ni < 4; ++ni)
#pragma unroll
            for (int r = 0; r < 4; ++r) {
                int row = wm * 64 + mi * 16 + quad * 4 + r;
                int col = wn * 64 + ni * 16 + cl;
                float v = acc[mi][ni][r];
                if (wn == 1) {  // vals half
                    v += bv[a * 64 + (col - 64)];
                    v = (v >= 0.f) ? v : 0.01f * v;
                }
                sm[row * 132 + col] = f2bfs(v);
            }
    __syncthreads();

    // ---- attention: each wave handles 4 b's; lane = d ----
#pragma unroll
    for (int t = 0; t < 4; ++t) {
        int lb = wid * 4 + t;
        float lg[8], vv[8];
#pragma unroll
        for (int e = 0; e < 8; ++e) {
            int row = lb * 8 + e;
            float kv = bfs2f(sm[row * 132 + lane]);
            vv[e] = bfs2f(sm[row * 132 + 64 + lane]);
            float p = sv[t] * kv;
#pragma unroll
            for (int m = 32; m; m >>= 1) p += __shfl_xor(p, m);
            lg[e] = p * 0.125f;  // 1/sqrt(d)
        }
        float mx = lg[0];
#pragma unroll
        for (int e = 1; e < 8; ++e) mx = fmaxf(mx, lg[e]);
        float ssum = 0.f, w[8];
#pragma unroll
        for (int e = 0; e < 8; ++e) { w[e] = __expf(lg[e] - mx); ssum += w[e]; }
        float inv = 1.f / ssum;
        float at = 0.f;
#pragma unroll
        for (int e = 0; e < 8; ++e) at += vv[e] * (w[e] * inv);
        long o = (bgBase + lb) * 512 + a * 64 + lane;
        actor_f32[o] = at;
        attn_bf[o] = f2bf(at);
    }
}

// ---------------------------------------------------------------------------
extern "C" void kernel_launch(void* const* d_in, const int* in_sizes, int n_in,
                              void* d_out, int out_size, void* d_ws, size_t ws_size,
                              hipStream_t stream) {
    (void)in_sizes; (void)n_in; (void)out_size;
    const float* states      = (const float*)d_in[0];
    const float* pre_actions = (const float*)d_in[1];
    const float* W_enc       = (const float*)d_in[2];
    const float* b_enc       = (const float*)d_in[3];
    const float* W_pre       = (const float*)d_in[4];
    const float* b_pre       = (const float*)d_in[5];
    const float* Wk          = (const float*)d_in[6];
    const float* Wsel        = (const float*)d_in[7];
    const float* Wv          = (const float*)d_in[8];
    const float* bv          = (const float*)d_in[9];
    const float* W_actor     = (const float*)d_in[10];
    const float* b_actor     = (const float*)d_in[11];
    const float* W_mean      = (const float*)d_in[12];
    const float* b_mean      = (const float*)d_in[13];
    const float* W_logstd    = (const float*)d_in[14];
    const float* b_logstd    = (const float*)d_in[15];

    char* ws = (char*)d_ws;
    size_t off = 0;
    auto alloc = [&](size_t bytes) -> void* {
        void* p = ws + off;
        off = (off + bytes + 255) & ~(size_t)255;
        return p;
    };
    float* mu_rstd = (float*)alloc((size_t)E_ * 64 * 2 * 4);
    float* bnpart  = (float*)alloc((size_t)E_ * 64 * 64 * 2 * 4);
    bf16* WencfT   = (bf16*)alloc((size_t)E_ * 512 * 64 * 2);
    float* bencf   = (float*)alloc((size_t)E_ * 512 * 4);
    bf16* WpreT    = (bf16*)alloc((size_t)512 * 512 * 2);
    bf16* WselT    = (bf16*)alloc((size_t)512 * 512 * 2);
    bf16* WkvaT    = (bf16*)alloc((size_t)1024 * 512 * 2);
    bf16* WactorT  = (bf16*)alloc((size_t)512 * 512 * 2);
    bf16* WmlT     = (bf16*)alloc((size_t)128 * 512 * 2);
    bf16* pa_bf    = (bf16*)alloc((size_t)B_ * 512 * 2);   // aliased later as p_attn
    bf16* p_pre    = (bf16*)alloc((size_t)B_ * 512 * 2);   // aliased later as p_x
    float* p_sel   = (float*)alloc((size_t)B_ * 512 * 4);
    bf16* p_attn = pa_bf;   // pre_actions bf16 dead after pre GEMM
    bf16* p_x    = p_pre;   // pre dead after sel GEMM

    // chunk over B: per-chunk bytes = Bc*(E*64*2) + Bc*(E*512*2) = Bc*9216
    size_t remaining = (ws_size > off) ? ws_size - off : 0;
    int Bc = B_;
    while (Bc > 128 && (size_t)Bc * 9216 + 4096 > remaining) Bc >>= 1;
    const int NC = B_ / Bc;
    bf16* c_sbf  = (bf16*)alloc((size_t)E_ * Bc * 64 * 2);
    bf16* c_encs = (bf16*)alloc((size_t)E_ * Bc * 512 * 2);  // [b][e][512]

    // --- prep (one fused dispatch + BN chain) ---
    packAll<<<13568, 256, 0, stream>>>(W_pre, W_actor, Wsel, Wk, Wv, W_mean, W_logstd,
                                       pre_actions, WpreT, WactorT, WselT, WkvaT, WmlT,
                                       pa_bf);
    bnPart<<<512, 256, 0, stream>>>(states, bnpart);
    bnFin<<<2, 256, 0, stream>>>(bnpart, mu_rstd);
    foldEnc<<<16, 256, 0, stream>>>(W_enc, b_enc, mu_rstd, WencfT, bencf);

    // --- pre / sel (full B) ---
    gemm_bt<1, 0, true, 2><<<dim3((B_ / 128) << 2, 1, 1), 256, 0, stream>>>(
        pa_bf, WpreT, b_pre, nullptr, p_pre, nullptr, B_, 512, 512, 0, 0, 0, 0);
    gemm_bt<0, 1, false, 2><<<dim3((B_ / 128) << 2, 1, 1), 256, 0, stream>>>(
        p_pre, WselT, nullptr, nullptr, p_sel, nullptr, B_, 512, 512, 0, 0, 0, 0);

    // --- chunked: states->bf16, encoder GEMM ([b][e][512]), fused kv+attn ---
    float* actor_out = (float*)d_out + 2L * B_ * 64;
    for (int c = 0; c < NC; ++c) {
        int b0 = c * Bc;
        cvt4_batched<<<dim3((Bc * 64 / 4 + 255) / 256, 1, E_), 256, 0, stream>>>(
            states + (long)b0 * 64, c_sbf, (long)B_ * 64, (long)Bc * 64, Bc * 64 / 4);
        gemm_bt<1, 4, true, 2><<<dim3((Bc / 128) << 2, 1, E_), 256, 0, stream>>>(
            c_sbf, WencfT, bencf, nullptr, c_encs, nullptr, Bc, 512, 64,
            (long)Bc * 64, (long)512 * 64, 512, 0);
        kv_attn<<<dim3((Bc / 16) * 8, 1, 1), 256, 0, stream>>>(
            c_encs, WkvaT, bv, p_sel, actor_out, p_attn, b0);
    }

    // --- actor + heads ---
    gemm_bt<2, 0, true, 2><<<dim3((B_ / 128) << 2, 1, 1), 256, 0, stream>>>(
        p_attn, WactorT, b_actor, nullptr, p_x, nullptr, B_, 512, 512, 0, 0, 0, 0);
    gemm_bt<0, 2, false, 0><<<dim3(B_ / 128, 1, 1), 256, 0, stream>>>(
        p_x, WmlT, b_mean, b_logstd, (float*)d_out, (float*)d_out + (long)B_ * 64,
        B_, 128, 512, 0, 0, 0, 0);
}